// Round 10
// baseline (3389.812 us; speedup 1.0000x reference)
//
#include <hip/hip_runtime.h>
#include <hip/hip_bf16.h>
#include <math.h>

#define SEQ   1024
#define BATCH 256
#define IND   256
#define HID   256
#define NGATE 4

// ws layout:
//   wb : bf16 [2 parts][4 gates][256 j][256 k], swizzled rows (1 MiB) @ 0
//   hr : bf16 regions [2 slots][16 g][16 J][16 b][16 j]; each 8B word's
//        element-0 LSB is the step stamp (512 B/region, single writer) @ 1 MiB
#define WB_BYTES   (2 * NGATE * HID * 256 * 2)
#define REG_BYTES  512

// steady-state LDS map (after W-frag extraction; overlaps init W staging)
#define HBUF_OFF   0        // [2][8 kc][64 lane][16B] = 2 x 8 KiB
#define FLAG_OFF   16384    // int
#define HST_OFF    16448    // 512 B h transpose stage
#define OST_OFF    17024    // 1 KiB out transpose stage

typedef float  f32x4  __attribute__((ext_vector_type(4)));
typedef short  bf16x8 __attribute__((ext_vector_type(8)));
typedef unsigned long long u64;

__device__ __forceinline__ short f2bf(float x) {
    __hip_bfloat16 h = __float2bfloat16(x);
    return *reinterpret_cast<short*>(&h);
}

__device__ __forceinline__ bf16x8 pack8(const float4& a, const float4& b) {
    union { short sh[8]; bf16x8 v; } u;
    u.sh[0] = f2bf(a.x); u.sh[1] = f2bf(a.y); u.sh[2] = f2bf(a.z); u.sh[3] = f2bf(a.w);
    u.sh[4] = f2bf(b.x); u.sh[5] = f2bf(b.y); u.sh[6] = f2bf(b.z); u.sh[7] = f2bf(b.w);
    return u.v;
}

__device__ __forceinline__ void gload_lds16(const void* g, void* l) {
    __builtin_amdgcn_global_load_lds(
        (const __attribute__((address_space(1))) unsigned int*)g,
        (__attribute__((address_space(3))) unsigned int*)l, 16, 0, 0);
}

__device__ __forceinline__ float sigmoid_f(float z) {
    return 1.f / (1.f + __expf(-z));
}
__device__ __forceinline__ float tanh_f(float v) {
    return 2.f / (1.f + __expf(-2.f * v)) - 1.f;
}

__device__ __forceinline__ bool stamp_ok(u64 q0, u64 q1, u64 ee) {
    return ((((q0 ^ ee) | (q1 ^ ee)) & 1ULL) == 0ULL);
}

// ---------------- prep kernels (unchanged from R9) ----------------

__global__ __launch_bounds__(256) void prep_w(
    const float* __restrict__ Wf, const float* __restrict__ Wi,
    const float* __restrict__ Wg, const float* __restrict__ Wo,
    unsigned char* __restrict__ wb)
{
    int chunk = blockIdx.x * 256 + threadIdx.x;   // 65536 chunks of 8 floats
    int g  = chunk >> 14;
    int jj = (chunk >> 6) & 255;
    int k0 = (chunk & 63) * 8;
    int p  = k0 >> 8;
    int kk = k0 & 255;
    const float* W = (g == 0) ? Wf : (g == 1) ? Wi : (g == 2) ? Wg : Wo;
    const float* src = W + (size_t)jj * 512 + k0;
    float4 a = *reinterpret_cast<const float4*>(src);
    float4 b = *reinterpret_cast<const float4*>(src + 4);
    size_t dstrow = (size_t)((p * 4 + g) * 256 + jj);
    *reinterpret_cast<bf16x8*>(
        wb + dstrow * 512 + ((kk * 2) ^ ((jj & 7) << 4))) = pack8(a, b);
}

__global__ __launch_bounds__(256) void prep_h0(
    const float* __restrict__ h0, unsigned char* __restrict__ hr)
{
    int idx  = blockIdx.x * 256 + threadIdx.x;    // 32768 chunks of 8 B
    int slot = idx >> 14;
    int g    = (idx >> 10) & 15;
    int J    = (idx >> 6) & 15;
    int c    = idx & 63;
    int br   = c >> 2;
    int j4   = (c & 3) * 4;
    const float* src = h0 + (size_t)(g * 16 + br) * HID + J * 16 + j4;
    unsigned short v[4];
    #pragma unroll
    for (int i = 0; i < 4; ++i)
        v[i] = (unsigned short)((unsigned short)f2bf(src[i]) | 1u);
    u64 q = (u64)v[0] | ((u64)v[1] << 16) | ((u64)v[2] << 32) | ((u64)v[3] << 48);
    *reinterpret_cast<u64*>(
        hr + (size_t)((slot * 16 + g) * 16 + J) * REG_BYTES + c * 8) = q;
}

// ---------------- persistent sequence kernel ----------------
// 256 blocks x 128 threads (2 waves). Wave 0 = compute (W frags in RF, MFMA,
// epilogue, stamped h store). Wave 1 = prober: 2-deep pipelined probing of the
// 16 group regions; fresh 16B words -> LDS hbuf[step&1]; LDS flag = step+1
// when its whole slice arrived. Compute chain: poll LDS flag -> ds_read ->
// MFMA -> epilogue -> LDS transpose -> ONE 8B stamped store/lane. The out
// store is deferred into the next step's wait shadow.
__global__ __launch_bounds__(128, 1) void lstm_seq(
    const float* __restrict__ x,  const float* __restrict__ c0,
    const float* __restrict__ bf_, const float* __restrict__ bi_,
    const float* __restrict__ bg_, const float* __restrict__ bo_,
    const unsigned char* __restrict__ wb, unsigned char* __restrict__ hr,
    float* __restrict__ out, float* __restrict__ hx, float* __restrict__ cxg)
{
    extern __shared__ __align__(16) unsigned char smem[];   // 64 KiB

    const int tid  = threadIdx.x;
    const int lane = tid & 63;
    const int w    = tid >> 6;
    const int blk  = blockIdx.x;
    const int g_   = blk & 15;          // batch group (XCD-local peers)
    const int J    = blk >> 4;          // j-tile 0..15
    const int j0   = J * 16;
    const int b0   = g_ * 16;

    const int lrow = lane & 15;
    const int hi   = lane >> 4;
    const int j    = j0 + lrow;

    // ---- stage W tile (64 KiB) into LDS once; both waves issue 32 rows each
    #pragma unroll
    for (int i = 0; i < 32; ++i) {
        int idx = w * 32 + i;
        gload_lds16(wb + ((size_t)((idx >> 3) * 256 + j0 + (idx & 7) * 2)) * 512
                       + lane * 16,
                    smem + idx * 1024);
    }
    __syncthreads();    // drains gload_lds

    // ---- wave0 extracts all W fragments into registers
    const int bswz = (lrow & 7) << 4;
    bf16x8 wf[2][8][4];
    if (w == 0) {
        #pragma unroll
        for (int p = 0; p < 2; ++p) {
            #pragma unroll
            for (int kc = 0; kc < 8; ++kc) {
                int wbyte = (kc * 64 + hi * 16) ^ bswz;
                #pragma unroll
                for (int gg = 0; gg < 4; ++gg)
                    wf[p][kc][gg] = *reinterpret_cast<const bf16x8*>(
                        smem + p * 32768 + gg * 8192 + lrow * 512 + wbyte);
            }
        }
    }
    __syncthreads();    // frag extraction done -> smem reusable
    if (tid == 0) *(volatile int*)(smem + FLAG_OFF) = 0;
    __syncthreads();

    unsigned char* regc[2] = {
        hr + (size_t)((0 * 16 + g_) * 16) * REG_BYTES,
        hr + (size_t)((1 * 16 + g_) * 16) * REG_BYTES };

    if (w == 1) {
        // ================= PROBER WAVE =================
        for (int s = 0; s < SEQ; ++s) {
            const u64 ee = (u64)(((unsigned)(s + 3) >> 1) & 1);
            const unsigned char* hsrc = regc[s & 1];
            unsigned char* dst = smem + HBUF_OFF + (s & 1) * 8192 + lane * 16;

            u64 qa0[8], qa1[8];
            #pragma unroll
            for (int kc = 0; kc < 8; ++kc) {
                const u64* p = reinterpret_cast<const u64*>(
                    hsrc + (2 * kc + (hi >> 1)) * REG_BYTES + lrow * 32 + (hi & 1) * 16);
                qa0[kc] = __hip_atomic_load(p,     __ATOMIC_RELAXED, __HIP_MEMORY_SCOPE_AGENT);
                qa1[kc] = __hip_atomic_load(p + 1, __ATOMIC_RELAXED, __HIP_MEMORY_SCOPE_AGENT);
            }
            unsigned done = 0;
            while (done != 0xffu) {
                // round B in flight before round A is consumed (counted vmcnt)
                u64 qb0[8], qb1[8];
                #pragma unroll
                for (int kc = 0; kc < 8; ++kc) {
                    const u64* p = reinterpret_cast<const u64*>(
                        hsrc + (2 * kc + (hi >> 1)) * REG_BYTES + lrow * 32 + (hi & 1) * 16);
                    qb0[kc] = __hip_atomic_load(p,     __ATOMIC_RELAXED, __HIP_MEMORY_SCOPE_AGENT);
                    qb1[kc] = __hip_atomic_load(p + 1, __ATOMIC_RELAXED, __HIP_MEMORY_SCOPE_AGENT);
                }
                #pragma unroll
                for (int kc = 0; kc < 8; ++kc) {
                    if (!((done >> kc) & 1) && stamp_ok(qa0[kc], qa1[kc], ee)) {
                        union { u64 q[2]; bf16x8 v; } u;
                        u.q[0] = qa0[kc]; u.q[1] = qa1[kc];
                        *reinterpret_cast<bf16x8*>(dst + kc * 1024) = u.v;
                        done |= (1u << kc);
                    }
                }
                #pragma unroll
                for (int kc = 0; kc < 8; ++kc) { qa0[kc] = qb0[kc]; qa1[kc] = qb1[kc]; }
            }
            // all lanes reconverged: publish
            __builtin_amdgcn_sched_barrier(0);
            asm volatile("s_waitcnt lgkmcnt(0)" ::: "memory");
            if (lane == 0) *(volatile int*)(smem + FLAG_OFF) = s + 1;
        }
        return;
    }

    // ================= COMPUTE WAVE =================
    __builtin_amdgcn_s_setprio(1);

    const float biasF = bf_[j], biasI = bi_[j], biasG = bg_[j], biasO = bo_[j];
    float cst[4];
    #pragma unroll
    for (int r = 0; r < 4; ++r)
        cst[r] = c0[(b0 + hi * 4 + r) * HID + j];

    // x pipeline: xpk = packed x(s); xt = in-flight x(s+1)
    float4 xt0[8], xt1[8];
    bf16x8 xpk[8];
    {
        const float* xr = x + (size_t)(b0 + lrow) * IND;
        #pragma unroll
        for (int kc = 0; kc < 8; ++kc) {
            const float* p = xr + kc * 32 + hi * 8;
            xt0[kc] = *reinterpret_cast<const float4*>(p);
            xt1[kc] = *reinterpret_cast<const float4*>(p + 4);
        }
        #pragma unroll
        for (int kc = 0; kc < 8; ++kc) xpk[kc] = pack8(xt0[kc], xt1[kc]);
        const float* xr1 = x + ((size_t)BATCH + b0 + lrow) * IND;
        #pragma unroll
        for (int kc = 0; kc < 8; ++kc) {
            const float* p = xr1 + kc * 32 + hi * 8;
            xt0[kc] = *reinterpret_cast<const float4*>(p);
            xt1[kc] = *reinterpret_cast<const float4*>(p + 4);
        }
    }

    unsigned char* regp[2] = { regc[0] + J * REG_BYTES, regc[1] + J * REG_BYTES };
    volatile int* flg = (volatile int*)(smem + FLAG_OFF);
    float hvprev[4] = {0.f, 0.f, 0.f, 0.f};

    for (int s = 0; s < SEQ; ++s) {
        // ---- phase A: x-part MFMA (pure register work)
        f32x4 aF = {0.f, 0.f, 0.f, 0.f};
        f32x4 aI = {0.f, 0.f, 0.f, 0.f};
        f32x4 aG = {0.f, 0.f, 0.f, 0.f};
        f32x4 aO = {0.f, 0.f, 0.f, 0.f};
        #pragma unroll
        for (int kc = 0; kc < 8; ++kc) {
            aF = __builtin_amdgcn_mfma_f32_16x16x32_bf16(xpk[kc], wf[0][kc][0], aF, 0, 0, 0);
            aI = __builtin_amdgcn_mfma_f32_16x16x32_bf16(xpk[kc], wf[0][kc][1], aI, 0, 0, 0);
            aG = __builtin_amdgcn_mfma_f32_16x16x32_bf16(xpk[kc], wf[0][kc][2], aG, 0, 0, 0);
            aO = __builtin_amdgcn_mfma_f32_16x16x32_bf16(xpk[kc], wf[0][kc][3], aO, 0, 0, 0);
        }

        // ---- shadow work while h round-trip is in flight:
        // pack x(s+1); issue x(s+2); store out[s-1] (deferred)
        #pragma unroll
        for (int kc = 0; kc < 8; ++kc) xpk[kc] = pack8(xt0[kc], xt1[kc]);
        if (s + 2 < SEQ) {
            const float* xr = x + ((size_t)(s + 2) * BATCH + b0 + lrow) * IND;
            #pragma unroll
            for (int kc = 0; kc < 8; ++kc) {
                const float* p = xr + kc * 32 + hi * 8;
                xt0[kc] = *reinterpret_cast<const float4*>(p);
                xt1[kc] = *reinterpret_cast<const float4*>(p + 4);
            }
        }
        if (s > 0) {
            #pragma unroll
            for (int r = 0; r < 4; ++r)
                *reinterpret_cast<float*>(
                    smem + OST_OFF + (hi * 4 + r) * 64 + lrow * 4) = hvprev[r];
            float4 ov = *reinterpret_cast<const float4*>(smem + OST_OFF + lane * 16);
            *reinterpret_cast<float4*>(
                out + (size_t)(s - 1) * (BATCH * HID)
                    + (size_t)(b0 + (lane >> 2)) * HID + j0 + (lane & 3) * 4) = ov;
        }
        __builtin_amdgcn_sched_barrier(0);

        // ---- wait for prober's flag, then h frags from LDS
        while (*flg < s + 1) {}
        __builtin_amdgcn_sched_barrier(0);
        const unsigned char* hb = smem + HBUF_OFF + (s & 1) * 8192;
        #pragma unroll
        for (int kc = 0; kc < 8; ++kc) {
            bf16x8 hf = *reinterpret_cast<const bf16x8*>(hb + kc * 1024 + lane * 16);
            aF = __builtin_amdgcn_mfma_f32_16x16x32_bf16(hf, wf[1][kc][0], aF, 0, 0, 0);
            aI = __builtin_amdgcn_mfma_f32_16x16x32_bf16(hf, wf[1][kc][1], aI, 0, 0, 0);
            aG = __builtin_amdgcn_mfma_f32_16x16x32_bf16(hf, wf[1][kc][2], aG, 0, 0, 0);
            aO = __builtin_amdgcn_mfma_f32_16x16x32_bf16(hf, wf[1][kc][3], aO, 0, 0, 0);
        }

        // ---- epilogue: gates + c update
        float hv[4];
        #pragma unroll
        for (int r = 0; r < 4; ++r) {
            float fg = sigmoid_f(aF[r] + biasF);
            float ig = sigmoid_f(aI[r] + biasI);
            float gg = tanh_f(aG[r] + biasG);
            float og = sigmoid_f(aO[r] + biasO);
            cst[r] = fg * cst[r] + ig * gg;
            hv[r]  = og * tanh_f(cst[r]);
        }

        // ---- h transpose via LDS (in-order per-wave DS) + stamped 8B store
        #pragma unroll
        for (int r = 0; r < 4; ++r)
            *reinterpret_cast<short*>(
                smem + HST_OFF + (hi * 4 + r) * 32 + lrow * 2) = f2bf(hv[r]);
        {
            u64 wv = *reinterpret_cast<const u64*>(smem + HST_OFF + lane * 8);
            wv = (wv & ~1ULL) | (u64)((s >> 1) & 1);
            __hip_atomic_store(
                reinterpret_cast<u64*>(regp[(s + 1) & 1] + lane * 8),
                wv, __ATOMIC_RELAXED, __HIP_MEMORY_SCOPE_AGENT);
        }

        #pragma unroll
        for (int r = 0; r < 4; ++r) hvprev[r] = hv[r];

        if (s == SEQ - 1) {
            // flush out[SEQ-1] + final states
            #pragma unroll
            for (int r = 0; r < 4; ++r)
                *reinterpret_cast<float*>(
                    smem + OST_OFF + (hi * 4 + r) * 64 + lrow * 4) = hv[r];
            float4 ov = *reinterpret_cast<const float4*>(smem + OST_OFF + lane * 16);
            *reinterpret_cast<float4*>(
                out + (size_t)s * (BATCH * HID)
                    + (size_t)(b0 + (lane >> 2)) * HID + j0 + (lane & 3) * 4) = ov;
            #pragma unroll
            for (int r = 0; r < 4; ++r) {
                int gi = (b0 + hi * 4 + r) * HID + j;
                hx[gi] = hv[r]; cxg[gi] = cst[r];
            }
        }
    }
}

extern "C" void kernel_launch(void* const* d_in, const int* in_sizes, int n_in,
                              void* d_out, int out_size, void* d_ws, size_t ws_size,
                              hipStream_t stream) {
    const float* x  = (const float*)d_in[0];
    const float* h0 = (const float*)d_in[1];
    const float* c0 = (const float*)d_in[2];
    const float* Wf = (const float*)d_in[3];
    const float* bf = (const float*)d_in[4];
    const float* Wi = (const float*)d_in[5];
    const float* bi = (const float*)d_in[6];
    const float* Wg = (const float*)d_in[7];
    const float* bg = (const float*)d_in[8];
    const float* Wo = (const float*)d_in[9];
    const float* bo = (const float*)d_in[10];

    float* out = (float*)d_out;
    float* hx  = out + (size_t)SEQ * BATCH * HID;
    float* cx  = hx + BATCH * HID;

    unsigned char* wb = (unsigned char*)d_ws;
    unsigned char* hr = wb + WB_BYTES;

    prep_w<<<256, 256, 0, stream>>>(Wf, Wi, Wg, Wo, wb);
    prep_h0<<<128, 256, 0, stream>>>(h0, hr);
    lstm_seq<<<256, 128, 65536, stream>>>(x, c0, bf, bi, bg, bo,
                                          wb, hr, out, hx, cx);
}